// Round 8
// baseline (276.247 us; speedup 1.0000x reference)
//
#include <hip/hip_runtime.h>
#include <hip/hip_bf16.h>
#include <stdint.h>

typedef __attribute__((ext_vector_type(8))) short bf16x8;
typedef __attribute__((ext_vector_type(4))) float f32x4;
typedef __hip_bfloat16 bf16_t;

#define D_MODEL 1024
#define NHEADS  16
#define DK      64
#define TSEQ    2048
#define BATCH   4
#define MTOK    (BATCH*TSEQ)   // 8192

// scale (1/sqrt(dk)) * log2(e), folded into wq/bq so QK^T is in exp2 domain
#define QSCALE 0.18033688011112042f

// attn LDS slot swizzle (64B rows): involution slot' = slot ^ FSWZ(row)
#define FSWZ(r) ((((r) & 3)) | ((((r) >> 3) & 1) << 2))

typedef __attribute__((address_space(3))) uint32_t lds_u32;
typedef const __attribute__((address_space(1))) uint32_t glb_u32;

__device__ __forceinline__ void load_lds16(const void* g, void* l) {
    // dest = wave-uniform base + lane*16 (linear); source is per-lane.
    __builtin_amdgcn_global_load_lds((glb_u32*)g, (lds_u32*)l, 16, 0, 0);
}

// ---------------- fp32 -> bf16 elementwise convert (x) ----------------
__global__ __launch_bounds__(256) void convert_x_kernel(const float* __restrict__ x,
                                                        bf16_t* __restrict__ out, int n4) {
    int i = blockIdx.x * 256 + threadIdx.x;
    if (i >= n4) return;
    float4 v = reinterpret_cast<const float4*>(x)[i];
    union { bf16_t h[4]; uint2 u; } p;
    p.h[0] = __float2bfloat16(v.x);
    p.h[1] = __float2bfloat16(v.y);
    p.h[2] = __float2bfloat16(v.z);
    p.h[3] = __float2bfloat16(v.w);
    reinterpret_cast<uint2*>(out)[i] = p.u;
}

// ------------- transpose + convert weights: Wt[n][k] = W[k][n] -------------
__global__ __launch_bounds__(256) void transpose_w_kernel(
    const float* __restrict__ w0, const float* __restrict__ w1,
    const float* __restrict__ w2, const float* __restrict__ w3,
    bf16_t* __restrict__ o0, bf16_t* __restrict__ o1,
    bf16_t* __restrict__ o2, bf16_t* __restrict__ o3) {
    const float* w = (blockIdx.z == 0) ? w0 : (blockIdx.z == 1) ? w1 : (blockIdx.z == 2) ? w2 : w3;
    bf16_t* o = (blockIdx.z == 0) ? o0 : (blockIdx.z == 1) ? o1 : (blockIdx.z == 2) ? o2 : o3;
    const float wscale = (blockIdx.z == 0) ? QSCALE : 1.0f;
    __shared__ float tile[32][33];
    int tx = threadIdx.x, ty = threadIdx.y;     // block (32,8)
    int bx = blockIdx.x * 32;                   // k tile
    int by = blockIdx.y * 32;                   // n tile
    #pragma unroll
    for (int i = 0; i < 4; ++i)
        tile[ty + i*8][tx] = w[(bx + ty + i*8) * D_MODEL + by + tx];
    __syncthreads();
    #pragma unroll
    for (int i = 0; i < 4; ++i)
        o[(by + ty + i*8) * D_MODEL + bx + tx] = __float2bfloat16(tile[tx][ty + i*8] * wscale);
}

// ======== Staged GEMM, double-buffered pipeline: C = A[M,K]*Bt[N,K]^T + bias ========
// (unchanged from round 7 — verified: vmcnt(8) counted, 2 barriers, XCD swizzle)
template<int FINAL>
__global__ __launch_bounds__(256) void gemm_staged_kernel(
    const bf16_t* __restrict__ A, const bf16_t* __restrict__ BtBase,
    const float* __restrict__ bias0, const float* __restrict__ bias1,
    const float* __restrict__ bias2, void* __restrict__ Cb) {
    const int K = D_MODEL;
    const int tid = threadIdx.x;
    const int wave = tid >> 6, lane = tid & 63;
    const int wm = wave >> 1, wn = wave & 1;          // 2x2 waves -> 128x128 tile

    // ---- bijective XCD swizzle (gridDim = (8, 64, z)) ----
    const int flat = blockIdx.x + 8 * (blockIdx.y + 64 * blockIdx.z);
    const int xcd = flat & 7;
    const int idx = flat >> 3;
    const int bx  = idx & 7;            // N-tile, fastest within XCD
    const int byl = (idx >> 3) & 7;     // 8 M-panels per XCD
    const int z   = FINAL ? 0 : (idx >> 6);
    const int by  = xcd * 8 + byl;

    const int mt = by * 128;                          // block tile bases (staging)
    const int nt = bx * 128;
    const int m0 = mt + wm * 64;                      // wave compute sub-tile
    const int n0 = nt + wn * 64;
    const bf16_t* Bt = BtBase + (size_t)z * (D_MODEL * D_MODEL);
    const float* bias = FINAL ? bias0 : (z == 0 ? bias0 : z == 1 ? bias1 : bias2);
    const float bscale = (!FINAL && z == 0) ? QSCALE : 1.0f;
    const int lr = lane & 15, lg = lane >> 4;

    __shared__ __align__(16) bf16_t Atile[2][128 * 64];   // 16 KB each, swizzled
    __shared__ __align__(16) bf16_t Btile[2][128 * 64];

    const int srow = wave * 32 + (lane >> 3);          // + i*8
    const int sl = (lane & 7) ^ (lane >> 3);           // logical k-slot (16B units)
    const size_t asrc0 = (size_t)(mt + srow) * K + sl * 8;
    const size_t bsrc0 = (size_t)(nt + srow) * K + sl * 8;

    f32x4 acc[4][4] = {};
    int cur = 0;
    #pragma unroll
    for (int i = 0; i < 4; ++i) {
        load_lds16(A  + asrc0 + (size_t)i * 8 * K, (char*)Atile[0] + wave * 4096 + i * 1024);
        load_lds16(Bt + bsrc0 + (size_t)i * 8 * K, (char*)Btile[0] + wave * 4096 + i * 1024);
    }

    #pragma unroll 1
    for (int k0 = 0; k0 < K; k0 += 64) {
        if (k0 + 64 < K) {
            #pragma unroll
            for (int i = 0; i < 4; ++i) {
                load_lds16(A  + asrc0 + (size_t)i * 8 * K + k0 + 64,
                           (char*)Atile[cur ^ 1] + wave * 4096 + i * 1024);
                load_lds16(Bt + bsrc0 + (size_t)i * 8 * K + k0 + 64,
                           (char*)Btile[cur ^ 1] + wave * 4096 + i * 1024);
            }
            asm volatile("s_waitcnt vmcnt(8)" ::: "memory");   // this tile's 8 done
        } else {
            asm volatile("s_waitcnt vmcnt(0)" ::: "memory");
        }
        __builtin_amdgcn_s_barrier();
        __builtin_amdgcn_sched_barrier(0);

        #pragma unroll
        for (int kk = 0; kk < 2; ++kk) {
            bf16x8 a[4], b[4];
            #pragma unroll
            for (int mi = 0; mi < 4; ++mi) {
                const int row = wm * 64 + mi * 16 + lr;
                a[mi] = *reinterpret_cast<const bf16x8*>(
                    (const char*)Atile[cur] + row * 128 + (((kk * 4 + lg) ^ (lr & 7)) * 16));
            }
            #pragma unroll
            for (int ni = 0; ni < 4; ++ni) {
                const int row = wn * 64 + ni * 16 + lr;
                b[ni] = *reinterpret_cast<const bf16x8*>(
                    (const char*)Btile[cur] + row * 128 + (((kk * 4 + lg) ^ (lr & 7)) * 16));
            }
            #pragma unroll
            for (int mi = 0; mi < 4; ++mi)
                #pragma unroll
                for (int ni = 0; ni < 4; ++ni)
                    acc[mi][ni] = __builtin_amdgcn_mfma_f32_16x16x32_bf16(a[mi], b[ni], acc[mi][ni], 0, 0, 0);
        }
        __builtin_amdgcn_sched_barrier(0);
        __builtin_amdgcn_s_barrier();   // all waves done reading buf[cur] before overwrite
        cur ^= 1;
    }
    // ---- epilogue ----
    #pragma unroll
    for (int mi = 0; mi < 4; ++mi) {
        #pragma unroll
        for (int ni = 0; ni < 4; ++ni) {
            const int col = n0 + ni * 16 + lr;
            const float bv = bias[col] * bscale;
            #pragma unroll
            for (int r = 0; r < 4; ++r) {
                const int row = m0 + mi * 16 + lg * 4 + r;
                const float val = acc[mi][ni][r] + bv;
                if (FINAL) {
                    reinterpret_cast<float*>(Cb)[(size_t)row * D_MODEL + col] = val;
                } else if (z <= 1) {
                    size_t idx2 = (size_t)z * (MTOK * D_MODEL) +
                        (((size_t)(row >> 11) * NHEADS + (col >> 6)) * TSEQ + (row & 2047)) * DK + (col & 63);
                    reinterpret_cast<bf16_t*>(Cb)[idx2] = __float2bfloat16(val);
                } else {
                    size_t idx2 = (size_t)2 * (MTOK * D_MODEL) +
                        (((size_t)(row >> 11) * NHEADS + (col >> 6)) * DK + (col & 63)) * TSEQ + (row & 2047);
                    reinterpret_cast<bf16_t*>(Cb)[idx2] = __float2bfloat16(val);
                }
            }
        }
    }
}

// ---- Flash attention v2: 8 waves x 32 q-rows (256-row q-tile), LDS K/V shared 2x wider ----
// Each wave owns TWO 16-row Q fragment groups (g=0,1); the 16KB of K/V LDS reads
// per step now feed 32 MFMA instead of 16 (LDS bytes and staging per q-row halved).
// Pairing {j, 7-j} -> every block exactly 36 kv-steps; grid 256 = 1 block/CU.
__global__ __launch_bounds__(512, 2) void attn_kernel(
    const bf16_t* __restrict__ Q, const bf16_t* __restrict__ K,
    const bf16_t* __restrict__ Vt, bf16_t* __restrict__ Y) {
    const int qpair = blockIdx.x;    // 0..3
    const int bh = blockIdx.y;       // b*16+h
    const int tid = threadIdx.x;
    const int wave = tid >> 6, lane = tid & 63;
    const int lr = lane & 15, lg = lane >> 4;

    const bf16_t* Qh = Q + (size_t)bh * TSEQ * DK;
    const bf16_t* Kh = K + (size_t)bh * TSEQ * DK;
    const bf16_t* Vh = Vt + (size_t)bh * DK * TSEQ;

    __shared__ __align__(16) char smem[2][16384];   // [buf][K 8KB | V 8KB]

    const int srow = tid >> 3;
    const int sslot = (tid & 7) ^ FSWZ(srow);
    const size_t koff = (size_t)srow * DK + sslot * 8;
    const size_t voff = (size_t)srow * TSEQ + sslot * 8;

    const int rbase = (lr >> 2) * 8 + (lr & 3);   // permuted K-row base (PV A-frag trick)
    const int bcast = (lane & 48) | (lg * 4);     // shfl src for row q=4*lg+r

    #pragma unroll 1
    for (int tt = 0; tt < 2; ++tt) {
        const int j = tt ? (7 - qpair) : qpair;   // 256-row q-tile index
        const int NT = 4 * j + 4;                 // kv steps of 64
        const int q0a = j * 256 + wave * 32;      // this wave's 32 q rows

        bf16x8 qf[2][2];
        #pragma unroll
        for (int g = 0; g < 2; ++g)
            #pragma unroll
            for (int kk = 0; kk < 2; ++kk)
                qf[g][kk] = *reinterpret_cast<const bf16x8*>(
                    &Qh[(size_t)(q0a + g*16 + lr) * DK + kk*32 + lg*8]);

        f32x4 o[2][4] = {};
        float mrun[2] = { -__builtin_inff(), -__builtin_inff() };
        float lrun[2] = { 0.f, 0.f };

        int cur = 0;
        load_lds16(Kh + koff, smem[0] + wave * 1024);
        load_lds16(Vh + voff, smem[0] + 8192 + wave * 1024);

        #pragma unroll 1
        for (int kt = 0; kt < NT; ++kt) {
            if (kt + 1 < NT) {
                load_lds16(Kh + (size_t)(kt + 1) * 64 * DK + koff, smem[cur ^ 1] + wave * 1024);
                load_lds16(Vh + (size_t)(kt + 1) * 64 + voff, smem[cur ^ 1] + 8192 + wave * 1024);
                asm volatile("s_waitcnt vmcnt(2)" ::: "memory");
            } else {
                asm volatile("s_waitcnt vmcnt(0)" ::: "memory");
            }
            __builtin_amdgcn_s_barrier();
            __builtin_amdgcn_sched_barrier(0);

            if (kt * 64 <= q0a + 31) {    // wave has at least one unmasked row
                const char* kb = smem[cur];
                // ---- S^T = K Q^T for both q-groups (K reads shared) ----
                f32x4 s[2][4] = {};
                __builtin_amdgcn_s_setprio(1);
                #pragma unroll
                for (int fk = 0; fk < 4; ++fk) {
                    const int krow = (fk >> 1)*32 + (fk & 1)*4 + rbase;
                    #pragma unroll
                    for (int kk = 0; kk < 2; ++kk) {
                        const bf16x8 kv = *reinterpret_cast<const bf16x8*>(
                            kb + krow*128 + (((kk*4 + lg) ^ FSWZ(krow)) * 16));
                        #pragma unroll
                        for (int g = 0; g < 2; ++g)
                            s[g][fk] = __builtin_amdgcn_mfma_f32_16x16x32_bf16(kv, qf[g][kk], s[g][fk], 0, 0, 0);
                    }
                }
                __builtin_amdgcn_s_setprio(0);
                // ---- causal mask (diagonal region only) ----
                if (kt * 64 + 63 > q0a) {
                    #pragma unroll
                    for (int g = 0; g < 2; ++g) {
                        const int qrow = q0a + g*16 + lr;
                        #pragma unroll
                        for (int fk = 0; fk < 4; ++fk) {
                            const int kb0 = kt*64 + (fk >> 1)*32 + lg*8 + (fk & 1)*4;
                            #pragma unroll
                            for (int r = 0; r < 4; ++r)
                                if (kb0 + r > qrow) s[g][fk][r] = -__builtin_inff();
                        }
                    }
                }
                // ---- row max per group ----
                float tmax[2];
                #pragma unroll
                for (int g = 0; g < 2; ++g) {
                    float t = s[g][0][0];
                    #pragma unroll
                    for (int fk = 0; fk < 4; ++fk)
                        #pragma unroll
                        for (int r = 0; r < 4; ++r)
                            t = fmaxf(t, s[g][fk][r]);
                    t = fmaxf(t, __shfl_xor(t, 16, 64));
                    t = fmaxf(t, __shfl_xor(t, 32, 64));
                    tmax[g] = t;
                }
                // ---- defer-max rescale (shared trigger) ----
                const float need = fmaxf(tmax[0] - mrun[0], tmax[1] - mrun[1]);
                if (__any(need > 11.5f)) {
                    float alpha[2];
                    #pragma unroll
                    for (int g = 0; g < 2; ++g) {
                        const float mnew = fmaxf(mrun[g], tmax[g]);
                        alpha[g] = exp2f(mrun[g] - mnew);
                        mrun[g] = mnew;
                        lrun[g] *= alpha[g];
                    }
                    #pragma unroll
                    for (int r = 0; r < 4; ++r) {
                        const float a0 = __shfl(alpha[0], bcast + r, 64);
                        const float a1 = __shfl(alpha[1], bcast + r, 64);
                        #pragma unroll
                        for (int fn = 0; fn < 4; ++fn) {
                            o[0][fn][r] *= a0;
                            o[1][fn][r] *= a1;
                        }
                    }
                }
                // ---- p = 2^(s-m), row sums ----
                #pragma unroll
                for (int g = 0; g < 2; ++g) {
                    float tsum = 0.f;
                    #pragma unroll
                    for (int fk = 0; fk < 4; ++fk)
                        #pragma unroll
                        for (int r = 0; r < 4; ++r) {
                            const float p = exp2f(s[g][fk][r] - mrun[g]);
                            s[g][fk][r] = p;
                            tsum += p;
                        }
                    tsum += __shfl_xor(tsum, 16, 64);
                    tsum += __shfl_xor(tsum, 32, 64);
                    lrun[g] += tsum;
                }
                // ---- pack P to A-fragments (lane-local) ----
                union { bf16x8 v; bf16_t h[8]; } pa[2][2];
                #pragma unroll
                for (int g = 0; g < 2; ++g)
                    #pragma unroll
                    for (int c = 0; c < 2; ++c)
                        #pragma unroll
                        for (int jj = 0; jj < 8; ++jj)
                            pa[g][c].h[jj] = __float2bfloat16(s[g][2*c + (jj >> 2)][jj & 3]);
                // ---- O += P V (V reads shared across groups) ----
                __builtin_amdgcn_s_setprio(1);
                #pragma unroll
                for (int fn = 0; fn < 4; ++fn) {
                    const int vrow = fn*16 + lr;
                    #pragma unroll
                    for (int c = 0; c < 2; ++c) {
                        const bf16x8 vv = *reinterpret_cast<const bf16x8*>(
                            kb + 8192 + vrow*128 + (((c*4 + lg) ^ FSWZ(vrow)) * 16));
                        #pragma unroll
                        for (int g = 0; g < 2; ++g)
                            o[g][fn] = __builtin_amdgcn_mfma_f32_16x16x32_bf16(pa[g][c].v, vv, o[g][fn], 0, 0, 0);
                    }
                }
                __builtin_amdgcn_s_setprio(0);
            }
            __builtin_amdgcn_sched_barrier(0);
            __builtin_amdgcn_s_barrier();
            cur ^= 1;
        }

        // ---- epilogue: divide by row sum, write Y[B,T,H,dk] ----
        const int b = bh >> 4, h = bh & 15;
        #pragma unroll
        for (int g = 0; g < 2; ++g)
            #pragma unroll
            for (int r = 0; r < 4; ++r) {
                const float lsum = __shfl(lrun[g], bcast + r, 64);
                const float inv = 1.f / lsum;
                const int t = q0a + g*16 + lg*4 + r;
                #pragma unroll
                for (int fn = 0; fn < 4; ++fn)
                    Y[(((size_t)b * TSEQ + t) * NHEADS + h) * DK + fn*16 + lr] =
                        __float2bfloat16(o[g][fn][r] * inv);
            }
    }
}

extern "C" void kernel_launch(void* const* d_in, const int* in_sizes, int n_in,
                              void* d_out, int out_size, void* d_ws, size_t ws_size,
                              hipStream_t stream) {
    const float* x  = (const float*)d_in[0];
    const float* wq = (const float*)d_in[1];
    const float* bq = (const float*)d_in[2];
    const float* wk = (const float*)d_in[3];
    const float* bk = (const float*)d_in[4];
    const float* wv = (const float*)d_in[5];
    const float* bv = (const float*)d_in[6];
    const float* wo = (const float*)d_in[7];
    const float* bo = (const float*)d_in[8];
    float* out = (float*)d_out;

    char* ws = (char*)d_ws;
    const size_t MB = 1u << 20;
    bf16_t* xb  = (bf16_t*)(ws);             // 16 MB  (reused as Y after QKV)
    bf16_t* Yb  = (bf16_t*)(ws);             // alias of xb (attention output)
    bf16_t* wqt = (bf16_t*)(ws + 16*MB);     // 2 MB each, contiguous (wq,wk,wv)
    bf16_t* wkt = (bf16_t*)(ws + 18*MB);
    bf16_t* wvt = (bf16_t*)(ws + 20*MB);
    bf16_t* wot = (bf16_t*)(ws + 22*MB);
    bf16_t* Qb  = (bf16_t*)(ws + 24*MB);     // 16 MB each, contiguous (Q,K,Vt)
    bf16_t* Kb  = (bf16_t*)(ws + 40*MB);
    bf16_t* Vtb = (bf16_t*)(ws + 56*MB);

    const int n4 = (MTOK * D_MODEL) / 4;
    convert_x_kernel<<<(n4 + 255) / 256, 256, 0, stream>>>(x, xb, n4);
    transpose_w_kernel<<<dim3(32, 32, 4), dim3(32, 8), 0, stream>>>(
        wq, wk, wv, wo, wqt, wkt, wvt, wot);

    // fused QKV projection: z in {0,1,2} -> Q,K,Vt
    gemm_staged_kernel<0><<<dim3(D_MODEL / 128, MTOK / 128, 3), 256, 0, stream>>>(
        xb, wqt, bq, bk, bv, Qb);

    attn_kernel<<<dim3(4, BATCH * NHEADS), 512, 0, stream>>>(Qb, Kb, Vtb, Yb);

    // out projection (fp32 output)
    gemm_staged_kernel<1><<<dim3(D_MODEL / 128, MTOK / 128, 1), 256, 0, stream>>>(
        Yb, wot, bo, nullptr, nullptr, out);
}